// Round 1
// baseline (375.892 us; speedup 1.0000x reference)
//
#include <hip/hip_runtime.h>
#include <hip/hip_bf16.h>

typedef __attribute__((ext_vector_type(8))) short short8;
typedef __attribute__((ext_vector_type(4))) short short4v;
typedef __attribute__((ext_vector_type(4))) float f32x4;
typedef __attribute__((ext_vector_type(4))) float float4v;

#define DEVFN static __device__ __forceinline__

// ---- problem constants ----
#define T_N   2048
#define S_N   512
#define L_N   1024
#define C_N   2048
#define H_N   16
#define HK_N  4
#define D_N   128
#define ST_N  2560   /* S+T  */
#define TOT_N 3584   /* L+S+T */
#define KV_N  512    /* HK*D  */

DEVFN short f2bf(float f) {
  union { float f; unsigned u; } v; v.f = f;
  return (short)((v.u + 0x7FFFu + ((v.u >> 16) & 1u)) >> 16);
}
DEVFN float bf2f(short s) {
  union { unsigned u; float f; } v; v.u = ((unsigned)(unsigned short)s) << 16;
  return v.f;
}
DEVFN void gload16(const void* g, void* l) {
  __builtin_amdgcn_global_load_lds(
      (__attribute__((address_space(1))) void*)(g),
      (__attribute__((address_space(3))) void*)(l), 16, 0, 0);
}

// ---------------- elementwise f32 -> bf16 convert (4/thread) ----------------
__global__ void k_cvt(const float* __restrict__ src, short* __restrict__ dst, int n4) {
  int i = blockIdx.x * 256 + threadIdx.x;
  if (i >= n4) return;
  float4v v = reinterpret_cast<const float4v*>(src)[i];
  short4v o;
  o[0] = f2bf(v[0]); o[1] = f2bf(v[1]); o[2] = f2bf(v[2]); o[3] = f2bf(v[3]);
  reinterpret_cast<short4v*>(dst)[i] = o;
}

// ---------------- RoPE cos/sin table: [2560][64] each ----------------
__global__ void k_rope_tab(float* __restrict__ ct, float* __restrict__ st) {
  int i = blockIdx.x * 256 + threadIdx.x;
  if (i >= ST_N * 64) return;
  int p = i >> 6, f = i & 63;
  float freq = expf(-(float)f * (logf(10000.0f) / 64.0f));
  float ang = (float)p * freq;
  ct[i] = cosf(ang);
  st[i] = sinf(ang);
}

// ---------------- RoPE apply (in-place ok), 8 elems (4 pairs)/thread --------
__global__ void k_rope(const short* __restrict__ in, short* __restrict__ out,
                       int n8, int cols, int pos_off,
                       const float* __restrict__ ct, const float* __restrict__ st) {
  int i = blockIdx.x * 256 + threadIdx.x;
  if (i >= n8) return;
  int e = i * 8;
  int r = e / cols;
  int c = e - r * cols;
  int pos = r + pos_off;
  int f0 = (c & 127) >> 1;                 // head-local pair index (mult of 4)
  float4v cv = *reinterpret_cast<const float4v*>(&ct[pos * 64 + f0]);
  float4v sv = *reinterpret_cast<const float4v*>(&st[pos * 64 + f0]);
  short8 xv = *reinterpret_cast<const short8*>(&in[e]);
  short8 o;
#pragma unroll
  for (int p = 0; p < 4; p++) {
    float x1 = bf2f(xv[2 * p]), x2 = bf2f(xv[2 * p + 1]);
    o[2 * p]     = f2bf(x1 * cv[p] - x2 * sv[p]);
    o[2 * p + 1] = f2bf(x1 * sv[p] + x2 * cv[p]);
  }
  *reinterpret_cast<short8*>(&out[e]) = o;
}

// ------- transpose + convert: in f32 [rows][cols] -> out bf16 [cols][rows] --
__global__ void k_tconv(const float* __restrict__ in, short* __restrict__ out,
                        int rows, int cols) {
  __shared__ float tile[32][33];
  int c0 = blockIdx.x * 32, r0 = blockIdx.y * 32;
  int tx = threadIdx.x, ty = threadIdx.y;   // (32,8)
#pragma unroll
  for (int i = 0; i < 4; i++)
    tile[ty + i * 8][tx] = in[(size_t)(r0 + ty + i * 8) * cols + c0 + tx];
  __syncthreads();
#pragma unroll
  for (int i = 0; i < 4; i++)
    out[(size_t)(c0 + ty + i * 8) * rows + r0 + tx] = f2bf(tile[tx][ty + i * 8]);
}

// ------- bf16 transpose of V_full head-slices: [3584][hk*128+d] -> Vt[hk][d][3584]
__global__ void k_tv(const short* __restrict__ vf, short* __restrict__ vt) {
  __shared__ short tile[32][33];
  int hk = blockIdx.z;
  int r0 = blockIdx.x * 32;   // key row
  int d0 = blockIdx.y * 32;   // d
  int tx = threadIdx.x, ty = threadIdx.y;
#pragma unroll
  for (int i = 0; i < 4; i++)
    tile[ty + i * 8][tx] = vf[(size_t)(r0 + ty + i * 8) * KV_N + hk * D_N + d0 + tx];
  __syncthreads();
  short* o = vt + (size_t)hk * D_N * TOT_N;
#pragma unroll
  for (int i = 0; i < 4; i++)
    o[(size_t)(d0 + ty + i * 8) * TOT_N + r0 + tx] = tile[tx][ty + i * 8];
}

// ---------------- bf16 GEMM: C[M][N] = A[M][K] * Bt[N][K]^T ----------------
// 128x128 tile, BK=32, 4 waves, global_load_lds(16B), 4-way XOR chunk swizzle
template <bool OUT_F32>
__global__ __launch_bounds__(256) void k_gemm(
    const short* __restrict__ A, const short* __restrict__ Bt,
    void* __restrict__ C, int M, int N, int K) {
  __shared__ short lA[128 * 32];
  __shared__ short lB[128 * 32];
  const int tid = threadIdx.x;
  const int w = tid >> 6, l = tid & 63;
  const int l15 = l & 15, lh = l >> 4;
  const int rb = blockIdx.y << 7, cb = blockIdx.x << 7;
  const int wr = (w >> 1) << 6, wc = (w & 1) << 6;
  f32x4 acc[4][4] = {};
  // staging: chunk c (of 512 16B chunks) -> row c>>2, k-chunk (c^(c>>2))&3
  const int c0 = tid, c1 = 256 + tid;
  const short* pa0 = &A[(size_t)(rb + (c0 >> 2)) * K + (((c0 ^ (c0 >> 2)) & 3) << 3)];
  const short* pa1 = &A[(size_t)(rb + (c1 >> 2)) * K + (((c1 ^ (c1 >> 2)) & 3) << 3)];
  const short* pb0 = &Bt[(size_t)(cb + (c0 >> 2)) * K + (((c0 ^ (c0 >> 2)) & 3) << 3)];
  const short* pb1 = &Bt[(size_t)(cb + (c1 >> 2)) * K + (((c1 ^ (c1 >> 2)) & 3) << 3)];
  char* la0 = (char*)lA + ((w * 64) << 4);
  char* la1 = (char*)lA + ((256 + w * 64) << 4);
  char* lb0 = (char*)lB + ((w * 64) << 4);
  char* lb1 = (char*)lB + ((256 + w * 64) << 4);
  const int sw = (lh ^ (l15 & 3)) << 3;   // swizzled k-offset (shorts) for frag reads
  for (int kt = 0; kt < K; kt += 32) {
    gload16(pa0 + kt, la0);
    gload16(pa1 + kt, la1);
    gload16(pb0 + kt, lb0);
    gload16(pb1 + kt, lb1);
    __syncthreads();
    short8 af[4], bg[4];
#pragma unroll
    for (int m = 0; m < 4; m++)
      af[m] = *reinterpret_cast<const short8*>(&lA[(wr + m * 16 + l15) * 32 + sw]);
#pragma unroll
    for (int n = 0; n < 4; n++)
      bg[n] = *reinterpret_cast<const short8*>(&lB[(wc + n * 16 + l15) * 32 + sw]);
#pragma unroll
    for (int m = 0; m < 4; m++)
#pragma unroll
      for (int n = 0; n < 4; n++)
        acc[m][n] = __builtin_amdgcn_mfma_f32_16x16x32_bf16(af[m], bg[n], acc[m][n], 0, 0, 0);
    __syncthreads();
  }
#pragma unroll
  for (int m = 0; m < 4; m++)
#pragma unroll
    for (int n = 0; n < 4; n++)
#pragma unroll
      for (int r = 0; r < 4; r++) {
        int row = rb + wr + m * 16 + lh * 4 + r;
        int col = cb + wc + n * 16 + l15;
        if (OUT_F32)
          reinterpret_cast<float*>(C)[(size_t)row * N + col] = acc[m][n][r];
        else
          reinterpret_cast<short*>(C)[(size_t)row * N + col] = f2bf(acc[m][n][r]);
      }
}

// ---------------- flash attention ----------------
// grid (32 qblocks, 16 heads), 4 waves; 64 q-rows/block (16/wave), 64-key tiles
__global__ __launch_bounds__(256) void k_attn(
    const short* __restrict__ Q,   // [2048][2048] roped (unscaled)
    const short* __restrict__ Kf,  // [3584][512]
    const short* __restrict__ Vt,  // [4][128][3584]
    short* __restrict__ Y) {       // [2048][2048]
  __shared__ short kl[64 * 128];   // swizzled K tile
  __shared__ short vl[128 * 64];   // swizzled Vt tile [d][key]
  __shared__ short pl[4 * 16 * 64];// per-wave P tile
  const int qb = blockIdx.x, h = blockIdx.y;
  const int hk = h >> 2;
  const int tid = threadIdx.x, w = tid >> 6, l = tid & 63;
  const int l15 = l & 15, lh = l >> 4;
  const int qbase = qb << 6;
  const int qrow0 = qbase + (w << 4);
  short8 aq[4];
#pragma unroll
  for (int kb = 0; kb < 4; kb++)
    aq[kb] = *reinterpret_cast<const short8*>(
        &Q[(size_t)(qrow0 + l15) * C_N + h * D_N + kb * 32 + lh * 8]);
  f32x4 yacc[8] = {};
  float m_r[4] = {-1e30f, -1e30f, -1e30f, -1e30f};
  float l_r[4] = {};
  const float scale = 0.08838834764831845f;  // 1/sqrt(128)
  const int nkt = (1663 + qbase) >> 6;       // 25 + qb tiles
  for (int kt = 0; kt < nkt; kt++) {
    // ---- stage K tile (64x128, 16 chunks/row) and Vt tile (128x64, 8 chunks/row)
#pragma unroll
    for (int it = 0; it < 4; it++) {
      int c = it * 256 + tid;
      int krow = c >> 4, kkc = c & 15;
      gload16(&Kf[(size_t)(kt * 64 + krow) * KV_N + hk * D_N + ((kkc ^ (krow & 7)) << 3)],
              (char*)kl + ((it * 256 + w * 64) << 4));
      int vrow = c >> 3, vkc = c & 7;
      gload16(&Vt[(size_t)hk * D_N * TOT_N + (size_t)vrow * TOT_N + kt * 64 + ((vkc ^ (vrow & 7)) << 3)],
              (char*)vl + ((it * 256 + w * 64) << 4));
    }
    __syncthreads();
    // ---- S = Q K^T for 4 key-groups of 16
    f32x4 s[4] = {};
#pragma unroll
    for (int g = 0; g < 4; g++) {
      int row = g * 16 + l15;
#pragma unroll
      for (int kb = 0; kb < 4; kb++) {
        short8 bk = *reinterpret_cast<const short8*>(
            (const char*)kl + row * 256 + ((((kb << 2) + lh) ^ (row & 7)) << 4));
        s[g] = __builtin_amdgcn_mfma_f32_16x16x32_bf16(aq[kb], bk, s[g], 0, 0, 0);
      }
    }
    const bool need_mask = (kt * 64 + 63) > (1536 + qrow0);
#pragma unroll
    for (int g = 0; g < 4; g++)
#pragma unroll
      for (int r = 0; r < 4; r++) {
        float v = s[g][r] * scale;
        if (need_mask) {
          int key = kt * 64 + g * 16 + l15;
          int qi = qrow0 + lh * 4 + r;
          if (key > 1536 + qi) v = -1e30f;
        }
        s[g][r] = v;
      }
    // ---- online softmax (rows live across 16-lane groups)
    float tm[4], sc[4];
#pragma unroll
    for (int r = 0; r < 4; r++)
      tm[r] = fmaxf(fmaxf(s[0][r], s[1][r]), fmaxf(s[2][r], s[3][r]));
#pragma unroll
    for (int off = 1; off < 16; off <<= 1)
#pragma unroll
      for (int r = 0; r < 4; r++)
        tm[r] = fmaxf(tm[r], __shfl_xor(tm[r], off, 64));
#pragma unroll
    for (int r = 0; r < 4; r++) {
      float mn = fmaxf(m_r[r], tm[r]);
      sc[r] = __expf(m_r[r] - mn);
      m_r[r] = mn;
    }
    float ts[4] = {};
#pragma unroll
    for (int g = 0; g < 4; g++)
#pragma unroll
      for (int r = 0; r < 4; r++) {
        float p = __expf(s[g][r] - m_r[r]);
        s[g][r] = p;
        ts[r] += p;
      }
#pragma unroll
    for (int off = 1; off < 16; off <<= 1)
#pragma unroll
      for (int r = 0; r < 4; r++)
        ts[r] += __shfl_xor(ts[r], off, 64);
#pragma unroll
    for (int r = 0; r < 4; r++)
      l_r[r] = l_r[r] * sc[r] + ts[r];
#pragma unroll
    for (int dg = 0; dg < 8; dg++)
#pragma unroll
      for (int r = 0; r < 4; r++)
        yacc[dg][r] *= sc[r];
    // ---- P (C-layout) -> LDS (A-layout source), bf16, swizzled
#pragma unroll
    for (int g = 0; g < 4; g++)
#pragma unroll
      for (int r = 0; r < 4; r++) {
        int prow = lh * 4 + r;
        int key = g * 16 + l15;
        int byt = (w << 11) + (prow << 7) + ((((key >> 3) ^ (prow & 7)) << 4)) + ((key & 7) << 1);
        *reinterpret_cast<short*>((char*)pl + byt) = f2bf(s[g][r]);
      }
    // ---- PV: yacc[dg] += P(16x32) * V(32x16) over 2 k-halves
#pragma unroll
    for (int kb2 = 0; kb2 < 2; kb2++) {
      short8 ap = *reinterpret_cast<const short8*>(
          (const char*)pl + (w << 11) + (l15 << 7) + (((((kb2 << 2) + lh) ^ (l15 & 7)) << 4)));
#pragma unroll
      for (int dg = 0; dg < 8; dg++) {
        int vrow = dg * 16 + l15;
        short8 bv = *reinterpret_cast<const short8*>(
            (const char*)vl + (vrow << 7) + (((((kb2 << 2) + lh) ^ (vrow & 7)) << 4)));
        yacc[dg] = __builtin_amdgcn_mfma_f32_16x16x32_bf16(ap, bv, yacc[dg], 0, 0, 0);
      }
    }
    __syncthreads();
  }
  // ---- epilogue: divide by softmax denom, store bf16
#pragma unroll
  for (int dg = 0; dg < 8; dg++)
#pragma unroll
    for (int r = 0; r < 4; r++) {
      int row = qrow0 + lh * 4 + r;
      int col = h * D_N + dg * 16 + l15;
      Y[(size_t)row * C_N + col] = f2bf(yacc[dg][r] / l_r[r]);
    }
}

// ---------------- host launcher ----------------
extern "C" void kernel_launch(void* const* d_in, const int* in_sizes, int n_in,
                              void* d_out, int out_size, void* d_ws, size_t ws_size,
                              hipStream_t stream) {
  const float* x      = (const float*)d_in[0];
  const float* stm    = (const float*)d_in[1];
  // d_in[2] = long_q: unused (its query rows are discarded by y[:, -T:])
  const float* long_k = (const float*)d_in[3];
  const float* long_v = (const float*)d_in[4];
  const float* Wq     = (const float*)d_in[5];
  const float* Wk     = (const float*)d_in[6];
  const float* Wv     = (const float*)d_in[7];
  const float* Wo     = (const float*)d_in[8];
  float* out = (float*)d_out;

  // ---- workspace carve (bf16 stored as short) ----
  short* seq  = (short*)d_ws;                       // [2560][2048]
  short* WqT  = seq  + (size_t)ST_N * C_N;          // [2048][2048]
  short* WkT  = WqT  + (size_t)C_N * C_N;           // [512][2048]
  short* WvT  = WkT  + (size_t)KV_N * C_N;          // [512][2048]
  short* WoT  = WvT  + (size_t)KV_N * C_N;          // [2048][2048]
  short* qbuf = WoT  + (size_t)C_N * C_N;           // [2048][2048]
  short* Kf   = qbuf + (size_t)T_N * C_N;           // [3584][512]
  short* Vf   = Kf   + (size_t)TOT_N * KV_N;        // [3584][512]
  short* Vt   = Vf   + (size_t)TOT_N * KV_N;        // [4][128][3584]
  short* ybuf = Vt   + (size_t)TOT_N * KV_N;        // [2048][2048]
  float* ctab = (float*)(ybuf + (size_t)T_N * C_N); // [2560][64]
  float* stab = ctab + (size_t)ST_N * 64;

  // ---- converts ----
  k_cvt<<<S_N * C_N / 4 / 256, 256, 0, stream>>>(stm, seq, S_N * C_N / 4);
  k_cvt<<<T_N * C_N / 4 / 256, 256, 0, stream>>>(x, seq + (size_t)S_N * C_N, T_N * C_N / 4);
  k_cvt<<<L_N * KV_N / 4 / 256, 256, 0, stream>>>(long_k, Kf, L_N * KV_N / 4);
  k_cvt<<<L_N * KV_N / 4 / 256, 256, 0, stream>>>(long_v, Vf, L_N * KV_N / 4);

  // ---- weight transposes ----
  k_tconv<<<dim3(C_N / 32, C_N / 32), dim3(32, 8), 0, stream>>>(Wq, WqT, C_N, C_N);
  k_tconv<<<dim3(KV_N / 32, C_N / 32), dim3(32, 8), 0, stream>>>(Wk, WkT, C_N, KV_N);
  k_tconv<<<dim3(KV_N / 32, C_N / 32), dim3(32, 8), 0, stream>>>(Wv, WvT, C_N, KV_N);
  k_tconv<<<dim3(C_N / 32, C_N / 32), dim3(32, 8), 0, stream>>>(Wo, WoT, C_N, C_N);

  // ---- RoPE table ----
  k_rope_tab<<<ST_N * 64 / 256, 256, 0, stream>>>(ctab, stab);

  // ---- projections (only x-part of seq feeds Q) ----
  k_gemm<false><<<dim3(C_N / 128, T_N / 128), 256, 0, stream>>>(
      seq + (size_t)S_N * C_N, WqT, qbuf, T_N, C_N, C_N);
  k_gemm<false><<<dim3(KV_N / 128, ST_N / 128), 256, 0, stream>>>(
      seq, WkT, Kf + (size_t)L_N * KV_N, ST_N, KV_N, C_N);
  k_gemm<false><<<dim3(KV_N / 128, ST_N / 128), 256, 0, stream>>>(
      seq, WvT, Vf + (size_t)L_N * KV_N, ST_N, KV_N, C_N);

  // ---- RoPE: q (positions 512..2559, in-place), k-seq (positions 0..2559, in-place)
  k_rope<<<T_N * C_N / 8 / 256, 256, 0, stream>>>(qbuf, qbuf, T_N * C_N / 8, C_N, S_N, ctab, stab);
  k_rope<<<ST_N * KV_N / 8 / 256, 256, 0, stream>>>(
      Kf + (size_t)L_N * KV_N, Kf + (size_t)L_N * KV_N, ST_N * KV_N / 8, KV_N, 0, ctab, stab);

  // ---- V transpose per kv-head ----
  k_tv<<<dim3(TOT_N / 32, D_N / 32, HK_N), dim3(32, 8), 0, stream>>>(Vf, Vt);

  // ---- attention ----
  k_attn<<<dim3(T_N / 64, H_N), 256, 0, stream>>>(qbuf, Kf, Vt, ybuf);

  // ---- output projection (f32 out) ----
  k_gemm<true><<<dim3(C_N / 128, T_N / 128), 256, 0, stream>>>(ybuf, WoT, out, T_N, C_N, C_N);
}

// Round 2
// 239.180 us; speedup vs baseline: 1.5716x; 1.5716x over previous
//
#include <hip/hip_runtime.h>
#include <hip/hip_bf16.h>

typedef __attribute__((ext_vector_type(8))) short short8;
typedef __attribute__((ext_vector_type(4))) short short4v;
typedef __attribute__((ext_vector_type(4))) float f32x4;
typedef __attribute__((ext_vector_type(4))) float float4v;

#define DEVFN static __device__ __forceinline__

// ---- problem constants ----
#define T_N   2048
#define S_N   512
#define L_N   1024
#define C_N   2048
#define H_N   16
#define HK_N  4
#define D_N   128
#define ST_N  2560   /* S+T  */
#define TOT_N 3584   /* L+S+T */
#define KV_N  512    /* HK*D  */

DEVFN short f2bf(float f) {
  union { float f; unsigned u; } v; v.f = f;
  return (short)((v.u + 0x7FFFu + ((v.u >> 16) & 1u)) >> 16);
}
DEVFN float bf2f(short s) {
  union { unsigned u; float f; } v; v.u = ((unsigned)(unsigned short)s) << 16;
  return v.f;
}
DEVFN void gload16(const void* g, void* l) {
  __builtin_amdgcn_global_load_lds(
      (__attribute__((address_space(1))) void*)(g),
      (__attribute__((address_space(3))) void*)(l), 16, 0, 0);
}

// ---------------- elementwise f32 -> bf16 convert (4/thread) ----------------
__global__ void k_cvt(const float* __restrict__ src, short* __restrict__ dst, int n4) {
  int i = blockIdx.x * 256 + threadIdx.x;
  if (i >= n4) return;
  float4v v = reinterpret_cast<const float4v*>(src)[i];
  short4v o;
  o[0] = f2bf(v[0]); o[1] = f2bf(v[1]); o[2] = f2bf(v[2]); o[3] = f2bf(v[3]);
  reinterpret_cast<short4v*>(dst)[i] = o;
}

// ---------------- RoPE cos/sin table: [2560][64] each ----------------
__global__ void k_rope_tab(float* __restrict__ ct, float* __restrict__ st) {
  int i = blockIdx.x * 256 + threadIdx.x;
  if (i >= ST_N * 64) return;
  int p = i >> 6, f = i & 63;
  float freq = expf(-(float)f * (logf(10000.0f) / 64.0f));
  float ang = (float)p * freq;
  ct[i] = cosf(ang);
  st[i] = sinf(ang);
}

// ---------------- RoPE apply (in-place ok), 8 elems (4 pairs)/thread --------
__global__ void k_rope(const short* __restrict__ in, short* __restrict__ out,
                       int n8, int cols, int pos_off,
                       const float* __restrict__ ct, const float* __restrict__ st) {
  int i = blockIdx.x * 256 + threadIdx.x;
  if (i >= n8) return;
  int e = i * 8;
  int r = e / cols;
  int c = e - r * cols;
  int pos = r + pos_off;
  int f0 = (c & 127) >> 1;                 // head-local pair index (mult of 4)
  float4v cv = *reinterpret_cast<const float4v*>(&ct[pos * 64 + f0]);
  float4v sv = *reinterpret_cast<const float4v*>(&st[pos * 64 + f0]);
  short8 xv = *reinterpret_cast<const short8*>(&in[e]);
  short8 o;
#pragma unroll
  for (int p = 0; p < 4; p++) {
    float x1 = bf2f(xv[2 * p]), x2 = bf2f(xv[2 * p + 1]);
    o[2 * p]     = f2bf(x1 * cv[p] - x2 * sv[p]);
    o[2 * p + 1] = f2bf(x1 * sv[p] + x2 * cv[p]);
  }
  *reinterpret_cast<short8*>(&out[e]) = o;
}

// ------- transpose + convert: in f32 [rows][cols] -> out bf16 [cols][rows] --
__global__ void k_tconv(const float* __restrict__ in, short* __restrict__ out,
                        int rows, int cols) {
  __shared__ float tile[32][33];
  int c0 = blockIdx.x * 32, r0 = blockIdx.y * 32;
  int tx = threadIdx.x, ty = threadIdx.y;   // (32,8)
#pragma unroll
  for (int i = 0; i < 4; i++)
    tile[ty + i * 8][tx] = in[(size_t)(r0 + ty + i * 8) * cols + c0 + tx];
  __syncthreads();
#pragma unroll
  for (int i = 0; i < 4; i++)
    out[(size_t)(c0 + ty + i * 8) * rows + r0 + tx] = f2bf(tile[tx][ty + i * 8]);
}

// ------- bf16 transpose of V_full head-slices: [3584][hk*128+d] -> Vt[hk][d][3584]
__global__ void k_tv(const short* __restrict__ vf, short* __restrict__ vt) {
  __shared__ short tile[32][33];
  int hk = blockIdx.z;
  int r0 = blockIdx.x * 32;   // key row
  int d0 = blockIdx.y * 32;   // d
  int tx = threadIdx.x, ty = threadIdx.y;
#pragma unroll
  for (int i = 0; i < 4; i++)
    tile[ty + i * 8][tx] = vf[(size_t)(r0 + ty + i * 8) * KV_N + hk * D_N + d0 + tx];
  __syncthreads();
  short* o = vt + (size_t)hk * D_N * TOT_N;
#pragma unroll
  for (int i = 0; i < 4; i++)
    o[(size_t)(d0 + ty + i * 8) * TOT_N + r0 + tx] = tile[tx][ty + i * 8];
}

// ---------------- bf16 GEMM core macro-parts ----------------
// 128x128 tile, BK=32, 4 waves, global_load_lds(16B), 4-way XOR chunk swizzle

// generic GEMM: C[M][N] = A[M][K] * Bt[N][K]^T, f32 out
template <bool OUT_F32>
__global__ __launch_bounds__(256) void k_gemm(
    const short* __restrict__ A, const short* __restrict__ Bt,
    void* __restrict__ C, int M, int N, int K) {
  __shared__ short lA[128 * 32];
  __shared__ short lB[128 * 32];
  const int tid = threadIdx.x;
  const int w = tid >> 6, l = tid & 63;
  const int l15 = l & 15, lh = l >> 4;
  const int rb = blockIdx.y << 7, cb = blockIdx.x << 7;
  const int wr = (w >> 1) << 6, wc = (w & 1) << 6;
  f32x4 acc[4][4] = {};
  const int c0 = tid, c1 = 256 + tid;
  const short* pa0 = &A[(size_t)(rb + (c0 >> 2)) * K + (((c0 ^ (c0 >> 2)) & 3) << 3)];
  const short* pa1 = &A[(size_t)(rb + (c1 >> 2)) * K + (((c1 ^ (c1 >> 2)) & 3) << 3)];
  const short* pb0 = &Bt[(size_t)(cb + (c0 >> 2)) * K + (((c0 ^ (c0 >> 2)) & 3) << 3)];
  const short* pb1 = &Bt[(size_t)(cb + (c1 >> 2)) * K + (((c1 ^ (c1 >> 2)) & 3) << 3)];
  char* la0 = (char*)lA + ((w * 64) << 4);
  char* la1 = (char*)lA + ((256 + w * 64) << 4);
  char* lb0 = (char*)lB + ((w * 64) << 4);
  char* lb1 = (char*)lB + ((256 + w * 64) << 4);
  const int sw = (lh ^ (l15 & 3)) << 3;
  for (int kt = 0; kt < K; kt += 32) {
    gload16(pa0 + kt, la0);
    gload16(pa1 + kt, la1);
    gload16(pb0 + kt, lb0);
    gload16(pb1 + kt, lb1);
    __syncthreads();
    short8 af[4], bg[4];
#pragma unroll
    for (int m = 0; m < 4; m++)
      af[m] = *reinterpret_cast<const short8*>(&lA[(wr + m * 16 + l15) * 32 + sw]);
#pragma unroll
    for (int n = 0; n < 4; n++)
      bg[n] = *reinterpret_cast<const short8*>(&lB[(wc + n * 16 + l15) * 32 + sw]);
#pragma unroll
    for (int m = 0; m < 4; m++)
#pragma unroll
      for (int n = 0; n < 4; n++)
        acc[m][n] = __builtin_amdgcn_mfma_f32_16x16x32_bf16(af[m], bg[n], acc[m][n], 0, 0, 0);
    __syncthreads();
  }
#pragma unroll
  for (int m = 0; m < 4; m++)
#pragma unroll
    for (int n = 0; n < 4; n++)
#pragma unroll
      for (int r = 0; r < 4; r++) {
        int row = rb + wr + m * 16 + lh * 4 + r;
        int col = cb + wc + n * 16 + l15;
        if (OUT_F32)
          reinterpret_cast<float*>(C)[(size_t)row * N + col] = acc[m][n][r];
        else
          reinterpret_cast<short*>(C)[(size_t)row * N + col] = f2bf(acc[m][n][r]);
      }
}

// merged QKV projection: A = seq [2560][2048], Bt = [WqT|WkT|WvT] [3072][2048]
// epilogue splits cols: [0,2048)->qbuf (rows>=512), [2048,2560)->Kf, [2560,3072)->Vf
__global__ __launch_bounds__(256) void k_gemm_qkv(
    const short* __restrict__ A, const short* __restrict__ Bt,
    short* __restrict__ qbuf, short* __restrict__ Kf, short* __restrict__ Vf) {
  const int Kd = C_N, Nn = 3072;
  __shared__ short lA[128 * 32];
  __shared__ short lB[128 * 32];
  const int tid = threadIdx.x;
  const int w = tid >> 6, l = tid & 63;
  const int l15 = l & 15, lh = l >> 4;
  const int rb = blockIdx.y << 7, cb = blockIdx.x << 7;
  const int wr = (w >> 1) << 6, wc = (w & 1) << 6;
  f32x4 acc[4][4] = {};
  const int c0 = tid, c1 = 256 + tid;
  const short* pa0 = &A[(size_t)(rb + (c0 >> 2)) * Kd + (((c0 ^ (c0 >> 2)) & 3) << 3)];
  const short* pa1 = &A[(size_t)(rb + (c1 >> 2)) * Kd + (((c1 ^ (c1 >> 2)) & 3) << 3)];
  const short* pb0 = &Bt[(size_t)(cb + (c0 >> 2)) * Kd + (((c0 ^ (c0 >> 2)) & 3) << 3)];
  const short* pb1 = &Bt[(size_t)(cb + (c1 >> 2)) * Kd + (((c1 ^ (c1 >> 2)) & 3) << 3)];
  char* la0 = (char*)lA + ((w * 64) << 4);
  char* la1 = (char*)lA + ((256 + w * 64) << 4);
  char* lb0 = (char*)lB + ((w * 64) << 4);
  char* lb1 = (char*)lB + ((256 + w * 64) << 4);
  const int sw = (lh ^ (l15 & 3)) << 3;
  for (int kt = 0; kt < Kd; kt += 32) {
    gload16(pa0 + kt, la0);
    gload16(pa1 + kt, la1);
    gload16(pb0 + kt, lb0);
    gload16(pb1 + kt, lb1);
    __syncthreads();
    short8 af[4], bg[4];
#pragma unroll
    for (int m = 0; m < 4; m++)
      af[m] = *reinterpret_cast<const short8*>(&lA[(wr + m * 16 + l15) * 32 + sw]);
#pragma unroll
    for (int n = 0; n < 4; n++)
      bg[n] = *reinterpret_cast<const short8*>(&lB[(wc + n * 16 + l15) * 32 + sw]);
#pragma unroll
    for (int m = 0; m < 4; m++)
#pragma unroll
      for (int n = 0; n < 4; n++)
        acc[m][n] = __builtin_amdgcn_mfma_f32_16x16x32_bf16(af[m], bg[n], acc[m][n], 0, 0, 0);
    __syncthreads();
  }
#pragma unroll
  for (int m = 0; m < 4; m++)
#pragma unroll
    for (int n = 0; n < 4; n++)
#pragma unroll
      for (int r = 0; r < 4; r++) {
        int row = rb + wr + m * 16 + lh * 4 + r;
        int col = cb + wc + n * 16 + l15;
        short v = f2bf(acc[m][n][r]);
        if (col < 2048) {
          if (row >= 512) qbuf[(size_t)(row - 512) * C_N + col] = v;
        } else if (col < 2560) {
          Kf[(size_t)(L_N + row) * KV_N + (col - 2048)] = v;
        } else {
          Vf[(size_t)(L_N + row) * KV_N + (col - 2560)] = v;
        }
      }
}

// ---------------- flash attention ----------------
// flat grid of 512 blocks, remapped for XCD-L2 kv-head locality + pair balance.
// 4 waves; 64 q-rows/block (16/wave), 64-key tiles, double-buffered K/V staging.
__global__ __launch_bounds__(256) void k_attn(
    const short* __restrict__ Q,   // [2048][2048] roped (unscaled)
    const short* __restrict__ Kf,  // [3584][512]
    const short* __restrict__ Vt,  // [4][128][3584]
    short* __restrict__ Y) {       // [2048][2048]
  __shared__ short kl[2][64 * 128];   // swizzled K tiles (16 KB each)
  __shared__ short vl[2][128 * 64];   // swizzled Vt tiles (16 KB each)
  __shared__ short pl[4 * 16 * 64];   // per-wave P tile
  // block remap: hk = f&3 (XCD kv-head locality), pair (f, f+256) balanced
  const int f = blockIdx.x;
  const int hk = f & 3;
  const int qraw = (f >> 2) & 31;
  const int hh = (f >> 7) & 3;
  const int qb = (f & 256) ? (31 - qraw) : qraw;
  const int h = hk * 4 + hh;
  const int tid = threadIdx.x, w = tid >> 6, l = tid & 63;
  const int l15 = l & 15, lh = l >> 4;
  const int qbase = qb << 6;
  const int qrow0 = qbase + (w << 4);
  short8 aq[4];
#pragma unroll
  for (int kb = 0; kb < 4; kb++)
    aq[kb] = *reinterpret_cast<const short8*>(
        &Q[(size_t)(qrow0 + l15) * C_N + h * D_N + kb * 32 + lh * 8]);
  short8 ones;
#pragma unroll
  for (int j = 0; j < 8; j++) ones[j] = (short)0x3F80;  // bf16 1.0
  f32x4 yacc[8] = {};
  float m_r[4] = {-3.0e38f, -3.0e38f, -3.0e38f, -3.0e38f};
  float l_r[4] = {};
  const float K2 = 0.12751744f;   // (1/sqrt(128)) * log2(e)
  const float THR = 90.0f;        // defer-max threshold in raw-logit units (~8 scaled)
  const int nkt = (1663 + qbase) >> 6;
  // staging source pointers / LDS chunk offsets
  const short* psk[4];
  const short* psv[4];
  int ldsoff[4];
#pragma unroll
  for (int it = 0; it < 4; it++) {
    int c = it * 256 + tid;
    int krow = c >> 4, kkc = c & 15;
    psk[it] = &Kf[(size_t)krow * KV_N + hk * D_N + ((kkc ^ (krow & 7)) << 3)];
    int vrow = c >> 3, vkc = c & 7;
    psv[it] = &Vt[(size_t)hk * D_N * TOT_N + (size_t)vrow * TOT_N + ((vkc ^ (vrow & 7)) << 3)];
    ldsoff[it] = (it * 256 + w * 64) << 4;
  }
  // prologue: stage tile 0 into buffer 0
#pragma unroll
  for (int it = 0; it < 4; it++) {
    gload16(psk[it], (char*)kl + ldsoff[it]);
    gload16(psv[it], (char*)vl + ldsoff[it]);
    psk[it] += 64 * KV_N;
    psv[it] += 64;
  }
  __syncthreads();
  int cur = 0;
  for (int kt = 0; kt < nkt; kt++) {
    // ---- issue stage of tile kt+1 into buffer cur^1 (flies during compute)
    if (kt + 1 < nkt) {
#pragma unroll
      for (int it = 0; it < 4; it++) {
        gload16(psk[it], (char*)kl + ((cur ^ 1) << 14) + ldsoff[it]);
        gload16(psv[it], (char*)vl + ((cur ^ 1) << 14) + ldsoff[it]);
        psk[it] += 64 * KV_N;
        psv[it] += 64;
      }
    }
    const char* kbuf = (const char*)kl + (cur << 14);
    const char* vbuf = (const char*)vl + (cur << 14);
    // ---- S = Q K^T (raw logits, scale folded into exp2)
    f32x4 s[4] = {};
#pragma unroll
    for (int g = 0; g < 4; g++) {
      int row = g * 16 + l15;
#pragma unroll
      for (int kb = 0; kb < 4; kb++) {
        short8 bk = *reinterpret_cast<const short8*>(
            kbuf + row * 256 + ((((kb << 2) + lh) ^ (row & 7)) << 4));
        s[g] = __builtin_amdgcn_mfma_f32_16x16x32_bf16(aq[kb], bk, s[g], 0, 0, 0);
      }
    }
    const bool need_mask = (kt * 64 + 63) > (1536 + qrow0);
    if (need_mask) {
#pragma unroll
      for (int g = 0; g < 4; g++)
#pragma unroll
        for (int r = 0; r < 4; r++) {
          int key = kt * 64 + g * 16 + l15;
          int qi = qrow0 + lh * 4 + r;
          if (key > 1536 + qi) s[g][r] = -3.0e38f;
        }
    }
    // ---- defer-max online softmax (T13)
    float lm[4];
#pragma unroll
    for (int r = 0; r < 4; r++)
      lm[r] = fmaxf(fmaxf(s[0][r], s[1][r]), fmaxf(s[2][r], s[3][r]));
    bool ok = (lm[0] <= m_r[0] + THR) && (lm[1] <= m_r[1] + THR) &&
              (lm[2] <= m_r[2] + THR) && (lm[3] <= m_r[3] + THR);
    if (!__all(ok)) {
      float tm[4] = {lm[0], lm[1], lm[2], lm[3]};
#pragma unroll
      for (int off = 1; off < 16; off <<= 1)
#pragma unroll
        for (int r = 0; r < 4; r++)
          tm[r] = fmaxf(tm[r], __shfl_xor(tm[r], off, 64));
#pragma unroll
      for (int r = 0; r < 4; r++) {
        float mn = fmaxf(m_r[r], tm[r]);
        float scf = __builtin_amdgcn_exp2f((m_r[r] - mn) * K2);
        m_r[r] = mn;
        l_r[r] *= scf;
#pragma unroll
        for (int dg = 0; dg < 8; dg++) yacc[dg][r] *= scf;
      }
    }
    // ---- P = exp2((s-m)*K2) -> LDS (swizzled), bf16
#pragma unroll
    for (int g = 0; g < 4; g++)
#pragma unroll
      for (int r = 0; r < 4; r++) {
        float p = __builtin_amdgcn_exp2f((s[g][r] - m_r[r]) * K2);
        int prow = lh * 4 + r;
        int key = g * 16 + l15;
        int byt = (w << 11) + (prow << 7) + ((((key >> 3) ^ (prow & 7)) << 4)) + ((key & 7) << 1);
        *reinterpret_cast<short*>((char*)pl + byt) = f2bf(p);
      }
    // ---- PV + row-sum via mfma(P, ones)
    short8 ap0 = *reinterpret_cast<const short8*>(
        (const char*)pl + (w << 11) + (l15 << 7) + (((lh ^ (l15 & 7)) << 4)));
    short8 ap1 = *reinterpret_cast<const short8*>(
        (const char*)pl + (w << 11) + (l15 << 7) + ((((4 + lh) ^ (l15 & 7)) << 4)));
    f32x4 lsum = {};
    lsum = __builtin_amdgcn_mfma_f32_16x16x32_bf16(ap0, ones, lsum, 0, 0, 0);
    lsum = __builtin_amdgcn_mfma_f32_16x16x32_bf16(ap1, ones, lsum, 0, 0, 0);
#pragma unroll
    for (int dg = 0; dg < 8; dg++) {
      int vrow = dg * 16 + l15;
      short8 bv0 = *reinterpret_cast<const short8*>(
          vbuf + (vrow << 7) + (((lh ^ (vrow & 7)) << 4)));
      yacc[dg] = __builtin_amdgcn_mfma_f32_16x16x32_bf16(ap0, bv0, yacc[dg], 0, 0, 0);
      short8 bv1 = *reinterpret_cast<const short8*>(
          vbuf + (vrow << 7) + ((((4 + lh) ^ (vrow & 7)) << 4)));
      yacc[dg] = __builtin_amdgcn_mfma_f32_16x16x32_bf16(ap1, bv1, yacc[dg], 0, 0, 0);
    }
#pragma unroll
    for (int r = 0; r < 4; r++) l_r[r] += lsum[r];
    __syncthreads();
    cur ^= 1;
  }
  // ---- epilogue: divide by softmax denom, store bf16
#pragma unroll
  for (int dg = 0; dg < 8; dg++)
#pragma unroll
    for (int r = 0; r < 4; r++) {
      int row = qrow0 + lh * 4 + r;
      int col = h * D_N + dg * 16 + l15;
      Y[(size_t)row * C_N + col] = f2bf(yacc[dg][r] / l_r[r]);
    }
}

// ---------------- host launcher ----------------
extern "C" void kernel_launch(void* const* d_in, const int* in_sizes, int n_in,
                              void* d_out, int out_size, void* d_ws, size_t ws_size,
                              hipStream_t stream) {
  const float* x      = (const float*)d_in[0];
  const float* stm    = (const float*)d_in[1];
  // d_in[2] = long_q: unused (its query rows are discarded by y[:, -T:])
  const float* long_k = (const float*)d_in[3];
  const float* long_v = (const float*)d_in[4];
  const float* Wq     = (const float*)d_in[5];
  const float* Wk     = (const float*)d_in[6];
  const float* Wv     = (const float*)d_in[7];
  const float* Wo     = (const float*)d_in[8];
  float* out = (float*)d_out;

  // ---- workspace carve (bf16 stored as short) ----
  short* seq  = (short*)d_ws;                       // [2560][2048]
  short* WqT  = seq  + (size_t)ST_N * C_N;          // [2048][2048]  } contiguous:
  short* WkT  = WqT  + (size_t)C_N * C_N;           // [512][2048]   } Bt for merged
  short* WvT  = WkT  + (size_t)KV_N * C_N;          // [512][2048]   } QKV gemm
  short* WoT  = WvT  + (size_t)KV_N * C_N;          // [2048][2048]
  short* qbuf = WoT  + (size_t)C_N * C_N;           // [2048][2048]
  short* Kf   = qbuf + (size_t)T_N * C_N;           // [3584][512]
  short* Vf   = Kf   + (size_t)TOT_N * KV_N;        // [3584][512]
  short* Vt   = Vf   + (size_t)TOT_N * KV_N;        // [4][128][3584]
  short* ybuf = Vt   + (size_t)TOT_N * KV_N;        // [2048][2048]
  float* ctab = (float*)(ybuf + (size_t)T_N * C_N); // [2560][64]
  float* stab = ctab + (size_t)ST_N * 64;

  // ---- converts ----
  k_cvt<<<S_N * C_N / 4 / 256, 256, 0, stream>>>(stm, seq, S_N * C_N / 4);
  k_cvt<<<T_N * C_N / 4 / 256, 256, 0, stream>>>(x, seq + (size_t)S_N * C_N, T_N * C_N / 4);
  k_cvt<<<L_N * KV_N / 4 / 256, 256, 0, stream>>>(long_k, Kf, L_N * KV_N / 4);
  k_cvt<<<L_N * KV_N / 4 / 256, 256, 0, stream>>>(long_v, Vf, L_N * KV_N / 4);

  // ---- weight transposes ----
  k_tconv<<<dim3(C_N / 32, C_N / 32), dim3(32, 8), 0, stream>>>(Wq, WqT, C_N, C_N);
  k_tconv<<<dim3(KV_N / 32, C_N / 32), dim3(32, 8), 0, stream>>>(Wk, WkT, C_N, KV_N);
  k_tconv<<<dim3(KV_N / 32, C_N / 32), dim3(32, 8), 0, stream>>>(Wv, WvT, C_N, KV_N);
  k_tconv<<<dim3(C_N / 32, C_N / 32), dim3(32, 8), 0, stream>>>(Wo, WoT, C_N, C_N);

  // ---- RoPE table ----
  k_rope_tab<<<ST_N * 64 / 256, 256, 0, stream>>>(ctab, stab);

  // ---- merged QKV projection (480 blocks) ----
  k_gemm_qkv<<<dim3(3072 / 128, ST_N / 128), 256, 0, stream>>>(
      seq, WqT, qbuf, Kf, Vf);

  // ---- RoPE: q (positions 512..2559, in-place), k-seq (positions 0..2559, in-place)
  k_rope<<<T_N * C_N / 8 / 256, 256, 0, stream>>>(qbuf, qbuf, T_N * C_N / 8, C_N, S_N, ctab, stab);
  k_rope<<<ST_N * KV_N / 8 / 256, 256, 0, stream>>>(
      Kf + (size_t)L_N * KV_N, Kf + (size_t)L_N * KV_N, ST_N * KV_N / 8, KV_N, 0, ctab, stab);

  // ---- V transpose per kv-head ----
  k_tv<<<dim3(TOT_N / 32, D_N / 32, HK_N), dim3(32, 8), 0, stream>>>(Vf, Vt);

  // ---- attention ----
  k_attn<<<512, 256, 0, stream>>>(qbuf, Kf, Vt, ybuf);

  // ---- output projection (f32 out) ----
  k_gemm<true><<<dim3(C_N / 128, T_N / 128), 256, 0, stream>>>(ybuf, WoT, out, T_N, C_N, C_N);
}

// Round 3
// 228.398 us; speedup vs baseline: 1.6458x; 1.0472x over previous
//
#include <hip/hip_runtime.h>
#include <hip/hip_bf16.h>

typedef __attribute__((ext_vector_type(8))) short short8;
typedef __attribute__((ext_vector_type(4))) short short4v;
typedef __attribute__((ext_vector_type(4))) float f32x4;
typedef __attribute__((ext_vector_type(4))) float float4v;

#define DEVFN static __device__ __forceinline__

// ---- problem constants ----
#define T_N   2048
#define S_N   512
#define L_N   1024
#define C_N   2048
#define H_N   16
#define HK_N  4
#define D_N   128
#define ST_N  2560   /* S+T  */
#define TOT_N 3584   /* L+S+T */
#define KV_N  512    /* HK*D  */

DEVFN short f2bf(float f) {
  union { float f; unsigned u; } v; v.f = f;
  return (short)((v.u + 0x7FFFu + ((v.u >> 16) & 1u)) >> 16);
}
DEVFN float bf2f(short s) {
  union { unsigned u; float f; } v; v.u = ((unsigned)(unsigned short)s) << 16;
  return v.f;
}
DEVFN void gload16(const void* g, void* l) {
  __builtin_amdgcn_global_load_lds(
      (__attribute__((address_space(1))) void*)(g),
      (__attribute__((address_space(3))) void*)(l), 16, 0, 0);
}

// ---------------- elementwise f32 -> bf16 convert (4/thread) ----------------
__global__ void k_cvt(const float* __restrict__ src, short* __restrict__ dst, int n4) {
  int i = blockIdx.x * 256 + threadIdx.x;
  if (i >= n4) return;
  float4v v = reinterpret_cast<const float4v*>(src)[i];
  short4v o;
  o[0] = f2bf(v[0]); o[1] = f2bf(v[1]); o[2] = f2bf(v[2]); o[3] = f2bf(v[3]);
  reinterpret_cast<short4v*>(dst)[i] = o;
}

// ---------------- RoPE cos/sin table: [2560][64] each ----------------
__global__ void k_rope_tab(float* __restrict__ ct, float* __restrict__ st) {
  int i = blockIdx.x * 256 + threadIdx.x;
  if (i >= ST_N * 64) return;
  int p = i >> 6, f = i & 63;
  float freq = expf(-(float)f * (logf(10000.0f) / 64.0f));
  float ang = (float)p * freq;
  ct[i] = cosf(ang);
  st[i] = sinf(ang);
}

// ---------------- RoPE apply (in-place ok), 8 elems (4 pairs)/thread --------
__global__ void k_rope(const short* __restrict__ in, short* __restrict__ out,
                       int n8, int cols, int pos_off,
                       const float* __restrict__ ct, const float* __restrict__ st) {
  int i = blockIdx.x * 256 + threadIdx.x;
  if (i >= n8) return;
  int e = i * 8;
  int r = e / cols;
  int c = e - r * cols;
  int pos = r + pos_off;
  int f0 = (c & 127) >> 1;                 // head-local pair index (mult of 4)
  float4v cv = *reinterpret_cast<const float4v*>(&ct[pos * 64 + f0]);
  float4v sv = *reinterpret_cast<const float4v*>(&st[pos * 64 + f0]);
  short8 xv = *reinterpret_cast<const short8*>(&in[e]);
  short8 o;
#pragma unroll
  for (int p = 0; p < 4; p++) {
    float x1 = bf2f(xv[2 * p]), x2 = bf2f(xv[2 * p + 1]);
    o[2 * p]     = f2bf(x1 * cv[p] - x2 * sv[p]);
    o[2 * p + 1] = f2bf(x1 * sv[p] + x2 * cv[p]);
  }
  *reinterpret_cast<short8*>(&out[e]) = o;
}

// ------- transpose + convert: in f32 [rows][cols] -> out bf16 [cols][rows] --
__global__ void k_tconv(const float* __restrict__ in, short* __restrict__ out,
                        int rows, int cols) {
  __shared__ float tile[32][33];
  int c0 = blockIdx.x * 32, r0 = blockIdx.y * 32;
  int tx = threadIdx.x, ty = threadIdx.y;   // (32,8)
#pragma unroll
  for (int i = 0; i < 4; i++)
    tile[ty + i * 8][tx] = in[(size_t)(r0 + ty + i * 8) * cols + c0 + tx];
  __syncthreads();
#pragma unroll
  for (int i = 0; i < 4; i++)
    out[(size_t)(c0 + ty + i * 8) * rows + r0 + tx] = f2bf(tile[tx][ty + i * 8]);
}

// ------- bf16 transpose of V_full head-slices: [3584][hk*128+d] -> Vt[hk][d][3584]
__global__ void k_tv(const short* __restrict__ vf, short* __restrict__ vt) {
  __shared__ short tile[32][33];
  int hk = blockIdx.z;
  int r0 = blockIdx.x * 32;   // key row
  int d0 = blockIdx.y * 32;   // d
  int tx = threadIdx.x, ty = threadIdx.y;
#pragma unroll
  for (int i = 0; i < 4; i++)
    tile[ty + i * 8][tx] = vf[(size_t)(r0 + ty + i * 8) * KV_N + hk * D_N + d0 + tx];
  __syncthreads();
  short* o = vt + (size_t)hk * D_N * TOT_N;
#pragma unroll
  for (int i = 0; i < 4; i++)
    o[(size_t)(d0 + ty + i * 8) * TOT_N + r0 + tx] = tile[tx][ty + i * 8];
}

// ---------------- bf16 GEMM: C[M][N] = A[M][K] * Bt[N][K]^T ----------------
// 128x128 tile, BK=32, 4 waves, global_load_lds(16B), 4-way XOR chunk swizzle
template <bool OUT_F32>
__global__ __launch_bounds__(256) void k_gemm(
    const short* __restrict__ A, const short* __restrict__ Bt,
    void* __restrict__ C, int M, int N, int K) {
  __shared__ short lA[128 * 32];
  __shared__ short lB[128 * 32];
  const int tid = threadIdx.x;
  const int w = tid >> 6, l = tid & 63;
  const int l15 = l & 15, lh = l >> 4;
  const int rb = blockIdx.y << 7, cb = blockIdx.x << 7;
  const int wr = (w >> 1) << 6, wc = (w & 1) << 6;
  f32x4 acc[4][4] = {};
  const int c0 = tid, c1 = 256 + tid;
  const short* pa0 = &A[(size_t)(rb + (c0 >> 2)) * K + (((c0 ^ (c0 >> 2)) & 3) << 3)];
  const short* pa1 = &A[(size_t)(rb + (c1 >> 2)) * K + (((c1 ^ (c1 >> 2)) & 3) << 3)];
  const short* pb0 = &Bt[(size_t)(cb + (c0 >> 2)) * K + (((c0 ^ (c0 >> 2)) & 3) << 3)];
  const short* pb1 = &Bt[(size_t)(cb + (c1 >> 2)) * K + (((c1 ^ (c1 >> 2)) & 3) << 3)];
  char* la0 = (char*)lA + ((w * 64) << 4);
  char* la1 = (char*)lA + ((256 + w * 64) << 4);
  char* lb0 = (char*)lB + ((w * 64) << 4);
  char* lb1 = (char*)lB + ((256 + w * 64) << 4);
  const int sw = (lh ^ (l15 & 3)) << 3;
  for (int kt = 0; kt < K; kt += 32) {
    gload16(pa0 + kt, la0);
    gload16(pa1 + kt, la1);
    gload16(pb0 + kt, lb0);
    gload16(pb1 + kt, lb1);
    __syncthreads();
    short8 af[4], bg[4];
#pragma unroll
    for (int m = 0; m < 4; m++)
      af[m] = *reinterpret_cast<const short8*>(&lA[(wr + m * 16 + l15) * 32 + sw]);
#pragma unroll
    for (int n = 0; n < 4; n++)
      bg[n] = *reinterpret_cast<const short8*>(&lB[(wc + n * 16 + l15) * 32 + sw]);
#pragma unroll
    for (int m = 0; m < 4; m++)
#pragma unroll
      for (int n = 0; n < 4; n++)
        acc[m][n] = __builtin_amdgcn_mfma_f32_16x16x32_bf16(af[m], bg[n], acc[m][n], 0, 0, 0);
    __syncthreads();
  }
#pragma unroll
  for (int m = 0; m < 4; m++)
#pragma unroll
    for (int n = 0; n < 4; n++)
#pragma unroll
      for (int r = 0; r < 4; r++) {
        int row = rb + wr + m * 16 + lh * 4 + r;
        int col = cb + wc + n * 16 + l15;
        if (OUT_F32)
          reinterpret_cast<float*>(C)[(size_t)row * N + col] = acc[m][n][r];
        else
          reinterpret_cast<short*>(C)[(size_t)row * N + col] = f2bf(acc[m][n][r]);
      }
}

// merged QKV projection: A = seq [2560][2048], Bt = [WqT|WkT|WvT] [3072][2048]
__global__ __launch_bounds__(256) void k_gemm_qkv(
    const short* __restrict__ A, const short* __restrict__ Bt,
    short* __restrict__ qbuf, short* __restrict__ Kf, short* __restrict__ Vf) {
  const int Kd = C_N;
  __shared__ short lA[128 * 32];
  __shared__ short lB[128 * 32];
  const int tid = threadIdx.x;
  const int w = tid >> 6, l = tid & 63;
  const int l15 = l & 15, lh = l >> 4;
  const int rb = blockIdx.y << 7, cb = blockIdx.x << 7;
  const int wr = (w >> 1) << 6, wc = (w & 1) << 6;
  f32x4 acc[4][4] = {};
  const int c0 = tid, c1 = 256 + tid;
  const short* pa0 = &A[(size_t)(rb + (c0 >> 2)) * Kd + (((c0 ^ (c0 >> 2)) & 3) << 3)];
  const short* pa1 = &A[(size_t)(rb + (c1 >> 2)) * Kd + (((c1 ^ (c1 >> 2)) & 3) << 3)];
  const short* pb0 = &Bt[(size_t)(cb + (c0 >> 2)) * Kd + (((c0 ^ (c0 >> 2)) & 3) << 3)];
  const short* pb1 = &Bt[(size_t)(cb + (c1 >> 2)) * Kd + (((c1 ^ (c1 >> 2)) & 3) << 3)];
  char* la0 = (char*)lA + ((w * 64) << 4);
  char* la1 = (char*)lA + ((256 + w * 64) << 4);
  char* lb0 = (char*)lB + ((w * 64) << 4);
  char* lb1 = (char*)lB + ((256 + w * 64) << 4);
  const int sw = (lh ^ (l15 & 3)) << 3;
  for (int kt = 0; kt < Kd; kt += 32) {
    gload16(pa0 + kt, la0);
    gload16(pa1 + kt, la1);
    gload16(pb0 + kt, lb0);
    gload16(pb1 + kt, lb1);
    __syncthreads();
    short8 af[4], bg[4];
#pragma unroll
    for (int m = 0; m < 4; m++)
      af[m] = *reinterpret_cast<const short8*>(&lA[(wr + m * 16 + l15) * 32 + sw]);
#pragma unroll
    for (int n = 0; n < 4; n++)
      bg[n] = *reinterpret_cast<const short8*>(&lB[(wc + n * 16 + l15) * 32 + sw]);
#pragma unroll
    for (int m = 0; m < 4; m++)
#pragma unroll
      for (int n = 0; n < 4; n++)
        acc[m][n] = __builtin_amdgcn_mfma_f32_16x16x32_bf16(af[m], bg[n], acc[m][n], 0, 0, 0);
    __syncthreads();
  }
#pragma unroll
  for (int m = 0; m < 4; m++)
#pragma unroll
    for (int n = 0; n < 4; n++)
#pragma unroll
      for (int r = 0; r < 4; r++) {
        int row = rb + wr + m * 16 + lh * 4 + r;
        int col = cb + wc + n * 16 + l15;
        short v = f2bf(acc[m][n][r]);
        if (col < 2048) {
          if (row >= 512) qbuf[(size_t)(row - 512) * C_N + col] = v;
        } else if (col < 2560) {
          Kf[(size_t)(L_N + row) * KV_N + (col - 2048)] = v;
        } else {
          Vf[(size_t)(L_N + row) * KV_N + (col - 2560)] = v;
        }
      }
}

// ---------------- flash attention (swapped-QK, in-register P) ----------------
// 512 blocks remapped (hk = f&3 per XCD); 4 waves; 64 q-rows/block (16/wave).
// K staged with pi-permuted rows so S^T C-layout == PV A-frag key order.
// pi(l) bits [b5 b4 b3 b2 b1 b0] -> [b5 b3 b2 b4 b1 b0]
__global__ __launch_bounds__(256) void k_attn(
    const short* __restrict__ Q,   // [2048][2048] roped (unscaled)
    const short* __restrict__ Kf,  // [3584][512]
    const short* __restrict__ Vt,  // [4][128][3584]
    short* __restrict__ Y) {       // [2048][2048]
  __shared__ short kl[2][64 * 128];   // pi-row K tiles, dbuf (16 KB each)
  __shared__ short vl[128 * 64];      // V^T tile [d][key], single (16 KB)
  const int f = blockIdx.x;
  const int hk = f & 3;
  const int qraw = (f >> 2) & 31;
  const int hh = (f >> 7) & 3;
  const int qb = (f & 256) ? (31 - qraw) : qraw;
  const int h = hk * 4 + hh;
  const int tid = threadIdx.x, w = tid >> 6, l = tid & 63;
  const int l15 = l & 15, lh = l >> 4;
  const int qbase = qb << 6;
  const int qrow0 = qbase + (w << 4);
  // Q fragment (B operand): lane holds Q[qrow0+l15][kb*32 + lh*8 + j]
  short8 aq[4];
#pragma unroll
  for (int kb = 0; kb < 4; kb++)
    aq[kb] = *reinterpret_cast<const short8*>(
        &Q[(size_t)(qrow0 + l15) * C_N + h * D_N + kb * 32 + lh * 8]);
  short8 ones;
#pragma unroll
  for (int j = 0; j < 8; j++) ones[j] = (short)0x3F80;  // bf16 1.0
  f32x4 yacc[8] = {};
  f32x4 lacc = {};
  float m_r = -3.0e38f;            // per-lane: qrow = qrow0 + l15
  const float K2 = 0.12751744f;    // (1/sqrt(128)) * log2(e)
  const float THR = 90.0f;         // defer-max threshold (raw-logit units)
  const int nkt = (1663 + qbase) >> 6;
  // staging pointers: K uses pi-permuted rows, V linear
  const short* psk[4];
  const short* psv[4];
  int ldsoff[4];
#pragma unroll
  for (int it = 0; it < 4; it++) {
    int c = it * 256 + tid;
    int kr = c >> 4, kkc = c & 15;                       // LDS row, chunk
    int pkr = (kr & 0x23) | ((kr & 0x0C) << 1) | ((kr >> 2) & 4);  // pi(row)
    psk[it] = &Kf[(size_t)pkr * KV_N + hk * D_N + ((kkc ^ (kr & 7)) << 3)];
    int vrow = c >> 3, vkc = c & 7;
    psv[it] = &Vt[(size_t)hk * D_N * TOT_N + (size_t)vrow * TOT_N + ((vkc ^ (vrow & 7)) << 3)];
    ldsoff[it] = (it * 256 + w * 64) << 4;
  }
  // prologue: stage K(0) into kl[0]
#pragma unroll
  for (int it = 0; it < 4; it++)
    gload16(psk[it], (char*)kl + ldsoff[it]);
  __syncthreads();
  int cur = 0;
  for (int kt = 0; kt < nkt; kt++) {
    // ---- issue V(kt) into vl (4 loads/wave, oldest)
#pragma unroll
    for (int it = 0; it < 4; it++)
      gload16(psv[it] + (size_t)kt * 64, (char*)vl + ldsoff[it]);
    __builtin_amdgcn_sched_barrier(0);
    // ---- issue K(kt+1) into kl[cur^1] (4 loads/wave, newest)
    if (kt + 1 < nkt) {
#pragma unroll
      for (int it = 0; it < 4; it++)
        gload16(psk[it] + (size_t)(kt + 1) * 64 * KV_N,
                (char*)kl + ((cur ^ 1) << 14) + ldsoff[it]);
    }
    __builtin_amdgcn_sched_barrier(0);
    const char* kbuf = (const char*)kl + (cur << 14);
    // ---- S^T = K Q^T : s[g][r] = S[key = kt*64 + (g>>1)*32 + lh*8 + (g&1)*4 + r][qrow0 + l15]
    f32x4 s[4] = {};
    __builtin_amdgcn_s_setprio(1);
#pragma unroll
    for (int g = 0; g < 4; g++) {
      int row = g * 16 + l15;
#pragma unroll
      for (int kb = 0; kb < 4; kb++) {
        short8 bk = *reinterpret_cast<const short8*>(
            kbuf + row * 256 + ((((kb << 2) + lh) ^ (row & 7)) << 4));
        s[g] = __builtin_amdgcn_mfma_f32_16x16x32_bf16(bk, aq[kb], s[g], 0, 0, 0);
      }
    }
    __builtin_amdgcn_s_setprio(0);
    // ---- mask (boundary tiles only)
    if ((kt * 64 + 63) > (1536 + qrow0)) {
      int qi = qrow0 + l15;
#pragma unroll
      for (int g = 0; g < 4; g++)
#pragma unroll
        for (int r = 0; r < 4; r++) {
          int key = kt * 64 + ((g >> 1) << 5) + (lh << 3) + ((g & 1) << 2) + r;
          if (key > 1536 + qi) s[g][r] = -3.0e38f;
        }
    }
    // ---- defer-max online softmax (per-lane scalar m)
    float lm = s[0][0];
#pragma unroll
    for (int g = 0; g < 4; g++)
#pragma unroll
      for (int r = 0; r < 4; r++) lm = fmaxf(lm, s[g][r]);
    if (!__all(lm <= m_r + THR)) {
      float rm = fmaxf(lm, __shfl_xor(lm, 16, 64));
      rm = fmaxf(rm, __shfl_xor(rm, 32, 64));
      float mn = fmaxf(m_r, rm);
      float scf = __builtin_amdgcn_exp2f((m_r - mn) * K2);
      m_r = mn;
#pragma unroll
      for (int r = 0; r < 4; r++) {
        float sc_c = __shfl(scf, lh * 4 + r, 64);   // to C-layout row (lh,r)
        lacc[r] *= sc_c;
#pragma unroll
        for (int dg = 0; dg < 8; dg++) yacc[dg][r] *= sc_c;
      }
    }
    // ---- P = exp2(s*K2 - m*K2) packed straight into PV A-fragments
    const float mk = m_r * K2;
    short8 af[2];
#pragma unroll
    for (int g = 0; g < 4; g++)
#pragma unroll
      for (int r = 0; r < 4; r++) {
        float p = __builtin_amdgcn_exp2f(s[g][r] * K2 - mk);
        af[g >> 1][((g & 1) << 2) + r] = f2bf(p);
      }
    // ---- row sums via mfma(P, ones) -> C-layout (matches epilogue rows)
    lacc = __builtin_amdgcn_mfma_f32_16x16x32_bf16(af[0], ones, lacc, 0, 0, 0);
    lacc = __builtin_amdgcn_mfma_f32_16x16x32_bf16(af[1], ones, lacc, 0, 0, 0);
    // ---- wait own V loads (4 oldest; K(kt+1) keeps flying), sync waves
    if (kt + 1 < nkt) asm volatile("s_waitcnt vmcnt(4)" ::: "memory");
    else              asm volatile("s_waitcnt vmcnt(0)" ::: "memory");
    __builtin_amdgcn_s_barrier();   // raw: no auto vmcnt(0) drain
    // ---- PV: yacc[dg] += P(16x64) * V(64x128)
    __builtin_amdgcn_s_setprio(1);
#pragma unroll
    for (int kb2 = 0; kb2 < 2; kb2++)
#pragma unroll
      for (int dg = 0; dg < 8; dg++) {
        int vrow = dg * 16 + l15;
        short8 bv = *reinterpret_cast<const short8*>(
            (const char*)vl + (vrow << 7) + ((((kb2 << 2) + lh) ^ (vrow & 7)) << 4));
        yacc[dg] = __builtin_amdgcn_mfma_f32_16x16x32_bf16(af[kb2], bv, yacc[dg], 0, 0, 0);
      }
    __builtin_amdgcn_s_setprio(0);
    __syncthreads();   // end of tile: full drain (K(kt+1) landed), vl reusable
    cur ^= 1;
  }
  // ---- epilogue
#pragma unroll
  for (int dg = 0; dg < 8; dg++)
#pragma unroll
    for (int r = 0; r < 4; r++) {
      int row = qrow0 + lh * 4 + r;
      int col = h * D_N + dg * 16 + l15;
      Y[(size_t)row * C_N + col] = f2bf(yacc[dg][r] / lacc[r]);
    }
}

// ---------------- host launcher ----------------
extern "C" void kernel_launch(void* const* d_in, const int* in_sizes, int n_in,
                              void* d_out, int out_size, void* d_ws, size_t ws_size,
                              hipStream_t stream) {
  const float* x      = (const float*)d_in[0];
  const float* stm    = (const float*)d_in[1];
  // d_in[2] = long_q: unused (its query rows are discarded by y[:, -T:])
  const float* long_k = (const float*)d_in[3];
  const float* long_v = (const float*)d_in[4];
  const float* Wq     = (const float*)d_in[5];
  const float* Wk     = (const float*)d_in[6];
  const float* Wv     = (const float*)d_in[7];
  const float* Wo     = (const float*)d_in[8];
  float* out = (float*)d_out;

  // ---- workspace carve (bf16 stored as short) ----
  short* seq  = (short*)d_ws;                       // [2560][2048]
  short* WqT  = seq  + (size_t)ST_N * C_N;          // [2048][2048]  } contiguous:
  short* WkT  = WqT  + (size_t)C_N * C_N;           // [512][2048]   } Bt for merged
  short* WvT  = WkT  + (size_t)KV_N * C_N;          // [512][2048]   } QKV gemm
  short* WoT  = WvT  + (size_t)KV_N * C_N;          // [2048][2048]
  short* qbuf = WoT  + (size_t)C_N * C_N;           // [2048][2048]
  short* Kf   = qbuf + (size_t)T_N * C_N;           // [3584][512]
  short* Vf   = Kf   + (size_t)TOT_N * KV_N;        // [3584][512]
  short* Vt   = Vf   + (size_t)TOT_N * KV_N;        // [4][128][3584]
  short* ybuf = Vt   + (size_t)TOT_N * KV_N;        // [2048][2048]
  float* ctab = (float*)(ybuf + (size_t)T_N * C_N); // [2560][64]
  float* stab = ctab + (size_t)ST_N * 64;

  // ---- converts ----
  k_cvt<<<S_N * C_N / 4 / 256, 256, 0, stream>>>(stm, seq, S_N * C_N / 4);
  k_cvt<<<T_N * C_N / 4 / 256, 256, 0, stream>>>(x, seq + (size_t)S_N * C_N, T_N * C_N / 4);
  k_cvt<<<L_N * KV_N / 4 / 256, 256, 0, stream>>>(long_k, Kf, L_N * KV_N / 4);
  k_cvt<<<L_N * KV_N / 4 / 256, 256, 0, stream>>>(long_v, Vf, L_N * KV_N / 4);

  // ---- weight transposes ----
  k_tconv<<<dim3(C_N / 32, C_N / 32), dim3(32, 8), 0, stream>>>(Wq, WqT, C_N, C_N);
  k_tconv<<<dim3(KV_N / 32, C_N / 32), dim3(32, 8), 0, stream>>>(Wk, WkT, C_N, KV_N);
  k_tconv<<<dim3(KV_N / 32, C_N / 32), dim3(32, 8), 0, stream>>>(Wv, WvT, C_N, KV_N);
  k_tconv<<<dim3(C_N / 32, C_N / 32), dim3(32, 8), 0, stream>>>(Wo, WoT, C_N, C_N);

  // ---- RoPE table ----
  k_rope_tab<<<ST_N * 64 / 256, 256, 0, stream>>>(ctab, stab);

  // ---- merged QKV projection (480 blocks) ----
  k_gemm_qkv<<<dim3(3072 / 128, ST_N / 128), 256, 0, stream>>>(
      seq, WqT, qbuf, Kf, Vf);

  // ---- RoPE: q (positions 512..2559), k-seq (positions 0..2559), in-place
  k_rope<<<T_N * C_N / 8 / 256, 256, 0, stream>>>(qbuf, qbuf, T_N * C_N / 8, C_N, S_N, ctab, stab);
  k_rope<<<ST_N * KV_N / 8 / 256, 256, 0, stream>>>(
      Kf + (size_t)L_N * KV_N, Kf + (size_t)L_N * KV_N, ST_N * KV_N / 8, KV_N, 0, ctab, stab);

  // ---- V transpose per kv-head ----
  k_tv<<<dim3(TOT_N / 32, D_N / 32, HK_N), dim3(32, 8), 0, stream>>>(Vf, Vt);

  // ---- attention ----
  k_attn<<<512, 256, 0, stream>>>(qbuf, Kf, Vt, ybuf);

  // ---- output projection (f32 out) ----
  k_gemm<true><<<dim3(C_N / 128, T_N / 128), 256, 0, stream>>>(ybuf, WoT, out, T_N, C_N, C_N);
}

// Round 4
// 193.768 us; speedup vs baseline: 1.9399x; 1.1787x over previous
//
#include <hip/hip_runtime.h>
#include <hip/hip_bf16.h>

typedef __attribute__((ext_vector_type(8))) short short8;
typedef __attribute__((ext_vector_type(4))) short short4v;
typedef __attribute__((ext_vector_type(4))) float f32x4;
typedef __attribute__((ext_vector_type(4))) float float4v;
typedef __attribute__((ext_vector_type(4))) int i32x4;

#define DEVFN static __device__ __forceinline__

// ---- problem constants ----
#define T_N   2048
#define S_N   512
#define L_N   1024
#define C_N   2048
#define H_N   16
#define HK_N  4
#define D_N   128
#define ST_N  2560   /* S+T  */
#define TOT_N 3584   /* L+S+T */
#define KV_N  512    /* HK*D  */

DEVFN short f2bf(float f) {
  union { float f; unsigned u; } v; v.f = f;
  return (short)((v.u + 0x7FFFu + ((v.u >> 16) & 1u)) >> 16);
}
DEVFN float bf2f(short s) {
  union { unsigned u; float f; } v; v.u = ((unsigned)(unsigned short)s) << 16;
  return v.f;
}
DEVFN void gload16(const void* g, void* l) {
  __builtin_amdgcn_global_load_lds(
      (__attribute__((address_space(1))) void*)(g),
      (__attribute__((address_space(3))) void*)(l), 16, 0, 0);
}

// ---------------- fused setup: 4 converts + RoPE tables ----------------
#define Q_A (S_N * C_N / 4)
#define Q_B (Q_A + T_N * C_N / 4)
#define Q_C (Q_B + L_N * KV_N / 4)
#define Q_D (Q_C + L_N * KV_N / 4)
#define TAB_E (Q_D + ST_N * 64)
__global__ void k_setup(const float* __restrict__ x, const float* __restrict__ stm,
                        const float* __restrict__ lk, const float* __restrict__ lv,
                        short* __restrict__ seq, short* __restrict__ Kf,
                        short* __restrict__ Vf, float* __restrict__ ct,
                        float* __restrict__ st_) {
  int i = blockIdx.x * 256 + threadIdx.x;
  if (i < Q_D) {
    const float* src; short* dst; int off;
    if (i < Q_A)      { src = stm; dst = seq;                         off = i; }
    else if (i < Q_B) { src = x;   dst = seq + (size_t)S_N * C_N;     off = i - Q_A; }
    else if (i < Q_C) { src = lk;  dst = Kf;                          off = i - Q_B; }
    else              { src = lv;  dst = Vf;                          off = i - Q_C; }
    float4v v = reinterpret_cast<const float4v*>(src)[off];
    short4v o;
    o[0] = f2bf(v[0]); o[1] = f2bf(v[1]); o[2] = f2bf(v[2]); o[3] = f2bf(v[3]);
    reinterpret_cast<short4v*>(dst)[off] = o;
  } else {
    int j = i - Q_D;
    int p = j >> 6, fq = j & 63;
    float freq = expf(-(float)fq * (logf(10000.0f) / 64.0f));
    float ang = (float)p * freq;
    ct[j] = cosf(ang);
    st_[j] = sinf(ang);
  }
}

// ------- fused transpose+convert of all 4 weights: [2048][cols] -> [cols][2048]
__global__ void k_tconv_all(const float* __restrict__ Wq, const float* __restrict__ Wk,
                            const float* __restrict__ Wv, const float* __restrict__ Wo,
                            short* __restrict__ WqT, short* __restrict__ WkT,
                            short* __restrict__ WvT, short* __restrict__ WoT) {
  __shared__ float tile[32][33];
  const int z = blockIdx.z;
  const float* in = (z == 0) ? Wq : (z == 1) ? Wk : (z == 2) ? Wv : Wo;
  short* outp     = (z == 0) ? WqT : (z == 1) ? WkT : (z == 2) ? WvT : WoT;
  const int cols = (z == 1 || z == 2) ? KV_N : C_N;
  if (blockIdx.x * 32 >= cols) return;
  int c0 = blockIdx.x * 32, r0 = blockIdx.y * 32;
  int tx = threadIdx.x, ty = threadIdx.y;   // (32,8)
#pragma unroll
  for (int i = 0; i < 4; i++)
    tile[ty + i * 8][tx] = in[(size_t)(r0 + ty + i * 8) * cols + c0 + tx];
  __syncthreads();
#pragma unroll
  for (int i = 0; i < 4; i++)
    outp[(size_t)(c0 + ty + i * 8) * C_N + r0 + tx] = f2bf(tile[tx][ty + i * 8]);
}

// ------- bf16 transpose of V_full head-slices: [3584][hk*128+d] -> Vt[hk][d][3584]
__global__ void k_tv(const short* __restrict__ vf, short* __restrict__ vt) {
  __shared__ short tile[32][33];
  int hk = blockIdx.z;
  int r0 = blockIdx.x * 32;   // key row
  int d0 = blockIdx.y * 32;   // d
  int tx = threadIdx.x, ty = threadIdx.y;
#pragma unroll
  for (int i = 0; i < 4; i++)
    tile[ty + i * 8][tx] = vf[(size_t)(r0 + ty + i * 8) * KV_N + hk * D_N + d0 + tx];
  __syncthreads();
  short* o = vt + (size_t)hk * D_N * TOT_N;
#pragma unroll
  for (int i = 0; i < 4; i++)
    o[(size_t)(d0 + ty + i * 8) * TOT_N + r0 + tx] = tile[tx][ty + i * 8];
}

// ---------------- bf16 GEMM (2-phase dbuf): C = A[M][K] * Bt[N][K]^T ------
// 128x128 tile, BK=32, 4 waves, global_load_lds(16B), double-buffered staging.
template <bool OUT_F32>
__global__ __launch_bounds__(256) void k_gemm(
    const short* __restrict__ A, const short* __restrict__ Bt,
    void* __restrict__ C, int M, int N, int K) {
  __shared__ short lbuf[2 * 2 * 4096];   // [buf][A|B][4096 shorts] = 32 KB
  const int tid = threadIdx.x;
  const int w = tid >> 6, l = tid & 63;
  const int l15 = l & 15, lh = l >> 4;
  const int rb = blockIdx.y << 7, cb = blockIdx.x << 7;
  const int wr = (w >> 1) << 6, wc = (w & 1) << 6;
  f32x4 acc[4][4] = {};
  const int c0 = tid, c1 = 256 + tid;
  const short* pa0 = &A[(size_t)(rb + (c0 >> 2)) * K + (((c0 ^ (c0 >> 2)) & 3) << 3)];
  const short* pa1 = &A[(size_t)(rb + (c1 >> 2)) * K + (((c1 ^ (c1 >> 2)) & 3) << 3)];
  const short* pb0 = &Bt[(size_t)(cb + (c0 >> 2)) * K + (((c0 ^ (c0 >> 2)) & 3) << 3)];
  const short* pb1 = &Bt[(size_t)(cb + (c1 >> 2)) * K + (((c1 ^ (c1 >> 2)) & 3) << 3)];
  const int offA0 = (w * 64) << 4, offA1 = ((256 + w * 64) << 4);
  char* lbase = (char*)lbuf;
  const int sw = (lh ^ (l15 & 3)) << 3;
  // prologue
  {
    gload16(pa0, lbase + offA0);
    gload16(pa1, lbase + offA1);
    gload16(pb0, lbase + 8192 + offA0);
    gload16(pb1, lbase + 8192 + offA1);
  }
  int cur = 0;
  for (int kt = 0; kt < K; kt += 32) {
    const bool more = (kt + 32 < K);
    if (more) {
      char* p = lbase + ((cur ^ 1) << 14);
      gload16(pa0 + kt + 32, p + offA0);
      gload16(pa1 + kt + 32, p + offA1);
      gload16(pb0 + kt + 32, p + 8192 + offA0);
      gload16(pb1 + kt + 32, p + 8192 + offA1);
      asm volatile("s_waitcnt vmcnt(4)" ::: "memory");
    } else {
      asm volatile("s_waitcnt vmcnt(0)" ::: "memory");
    }
    __builtin_amdgcn_s_barrier();
    __builtin_amdgcn_sched_barrier(0);
    const short* la = (const short*)(lbase + (cur << 14));
    const short* lb = (const short*)(lbase + (cur << 14) + 8192);
    short8 af[4], bg[4];
#pragma unroll
    for (int m = 0; m < 4; m++)
      af[m] = *reinterpret_cast<const short8*>(&la[(wr + m * 16 + l15) * 32 + sw]);
#pragma unroll
    for (int n = 0; n < 4; n++)
      bg[n] = *reinterpret_cast<const short8*>(&lb[(wc + n * 16 + l15) * 32 + sw]);
    __builtin_amdgcn_s_setprio(1);
#pragma unroll
    for (int m = 0; m < 4; m++)
#pragma unroll
      for (int n = 0; n < 4; n++)
        acc[m][n] = __builtin_amdgcn_mfma_f32_16x16x32_bf16(af[m], bg[n], acc[m][n], 0, 0, 0);
    __builtin_amdgcn_s_setprio(0);
    asm volatile("s_waitcnt lgkmcnt(0)" ::: "memory");
    __builtin_amdgcn_sched_barrier(0);
    __builtin_amdgcn_s_barrier();
    __builtin_amdgcn_sched_barrier(0);
    cur ^= 1;
  }
#pragma unroll
  for (int m = 0; m < 4; m++)
#pragma unroll
    for (int n = 0; n < 4; n++)
#pragma unroll
      for (int r = 0; r < 4; r++) {
        int row = rb + wr + m * 16 + lh * 4 + r;
        int col = cb + wc + n * 16 + l15;
        if (OUT_F32)
          reinterpret_cast<float*>(C)[(size_t)row * N + col] = acc[m][n][r];
        else
          reinterpret_cast<short*>(C)[(size_t)row * N + col] = f2bf(acc[m][n][r]);
      }
}

// merged QKV projection (2-phase dbuf) + fused RoPE epilogue (f32 domain).
// A = seq [2560][2048], Bt = [WqT|WkT|WvT] [3072][2048]
__global__ __launch_bounds__(256) void k_gemm_qkv(
    const short* __restrict__ A, const short* __restrict__ Bt,
    short* __restrict__ qbuf, short* __restrict__ Kf, short* __restrict__ Vf,
    const float* __restrict__ ct, const float* __restrict__ st_) {
  const int Kd = C_N;
  __shared__ short lbuf[2 * 2 * 4096];
  const int tid = threadIdx.x;
  const int w = tid >> 6, l = tid & 63;
  const int l15 = l & 15, lh = l >> 4;
  const int rb = blockIdx.y << 7, cb = blockIdx.x << 7;
  const int wr = (w >> 1) << 6, wc = (w & 1) << 6;
  f32x4 acc[4][4] = {};
  const int c0 = tid, c1 = 256 + tid;
  const short* pa0 = &A[(size_t)(rb + (c0 >> 2)) * Kd + (((c0 ^ (c0 >> 2)) & 3) << 3)];
  const short* pa1 = &A[(size_t)(rb + (c1 >> 2)) * Kd + (((c1 ^ (c1 >> 2)) & 3) << 3)];
  const short* pb0 = &Bt[(size_t)(cb + (c0 >> 2)) * Kd + (((c0 ^ (c0 >> 2)) & 3) << 3)];
  const short* pb1 = &Bt[(size_t)(cb + (c1 >> 2)) * Kd + (((c1 ^ (c1 >> 2)) & 3) << 3)];
  const int offA0 = (w * 64) << 4, offA1 = ((256 + w * 64) << 4);
  char* lbase = (char*)lbuf;
  const int sw = (lh ^ (l15 & 3)) << 3;
  {
    gload16(pa0, lbase + offA0);
    gload16(pa1, lbase + offA1);
    gload16(pb0, lbase + 8192 + offA0);
    gload16(pb1, lbase + 8192 + offA1);
  }
  int cur = 0;
  for (int kt = 0; kt < Kd; kt += 32) {
    const bool more = (kt + 32 < Kd);
    if (more) {
      char* p = lbase + ((cur ^ 1) << 14);
      gload16(pa0 + kt + 32, p + offA0);
      gload16(pa1 + kt + 32, p + offA1);
      gload16(pb0 + kt + 32, p + 8192 + offA0);
      gload16(pb1 + kt + 32, p + 8192 + offA1);
      asm volatile("s_waitcnt vmcnt(4)" ::: "memory");
    } else {
      asm volatile("s_waitcnt vmcnt(0)" ::: "memory");
    }
    __builtin_amdgcn_s_barrier();
    __builtin_amdgcn_sched_barrier(0);
    const short* la = (const short*)(lbase + (cur << 14));
    const short* lb = (const short*)(lbase + (cur << 14) + 8192);
    short8 af[4], bg[4];
#pragma unroll
    for (int m = 0; m < 4; m++)
      af[m] = *reinterpret_cast<const short8*>(&la[(wr + m * 16 + l15) * 32 + sw]);
#pragma unroll
    for (int n = 0; n < 4; n++)
      bg[n] = *reinterpret_cast<const short8*>(&lb[(wc + n * 16 + l15) * 32 + sw]);
    __builtin_amdgcn_s_setprio(1);
#pragma unroll
    for (int m = 0; m < 4; m++)
#pragma unroll
      for (int n = 0; n < 4; n++)
        acc[m][n] = __builtin_amdgcn_mfma_f32_16x16x32_bf16(af[m], bg[n], acc[m][n], 0, 0, 0);
    __builtin_amdgcn_s_setprio(0);
    asm volatile("s_waitcnt lgkmcnt(0)" ::: "memory");
    __builtin_amdgcn_sched_barrier(0);
    __builtin_amdgcn_s_barrier();
    __builtin_amdgcn_sched_barrier(0);
    cur ^= 1;
  }
  // ---- epilogue with fused RoPE (pairs are adjacent lanes; shfl_xor(1)) ----
#pragma unroll
  for (int m = 0; m < 4; m++)
#pragma unroll
    for (int n = 0; n < 4; n++) {
      int coln = cb + wc + n * 16 + l15;
      const bool do_rope = coln < 2560;     // Q and K regions; V is not roped
      const int fidx = (coln & 127) >> 1;
#pragma unroll
      for (int r = 0; r < 4; r++) {
        int row = rb + wr + m * 16 + lh * 4 + r;
        float v = acc[m][n][r];
        float other = __shfl_xor(v, 1, 64);
        if (do_rope) {
          float co = ct[row * 64 + fidx];
          float si = st_[row * 64 + fidx];
          v = (l15 & 1) ? (other * si + v * co) : (v * co - other * si);
        }
        short bv = f2bf(v);
        if (coln < 2048) {
          if (row >= 512) qbuf[(size_t)(row - 512) * C_N + coln] = bv;
        } else if (coln < 2560) {
          Kf[(size_t)(L_N + row) * KV_N + (coln - 2048)] = bv;
        } else {
          Vf[(size_t)(L_N + row) * KV_N + (coln - 2560)] = bv;
        }
      }
    }
}

// ---------------- flash attention (swapped-QK, in-register P) ----------------
// 512 blocks remapped (hk = f&3 per XCD); 4 waves; 64 q-rows/block (16/wave).
// K,V both double-buffered; stage(t+2) at tile end; counted vmcnt(8) at top.
// K staged with pi-permuted rows so S^T C-layout == PV A-frag key order.
__global__ __launch_bounds__(256) void k_attn(
    const short* __restrict__ Q,   // [2048][2048] roped (unscaled)
    const short* __restrict__ Kf,  // [3584][512]
    const short* __restrict__ Vt,  // [4][128][3584]
    short* __restrict__ Y) {       // [2048][2048]
  __shared__ short kl[2][64 * 128];   // pi-row K tiles (16 KB each)
  __shared__ short vl[2][128 * 64];   // V^T tiles [d][key] (16 KB each)
  const int f = blockIdx.x;
  const int hk = f & 3;
  const int qraw = (f >> 2) & 31;
  const int hh = (f >> 7) & 3;
  const int qb = (f & 256) ? (31 - qraw) : qraw;
  const int h = hk * 4 + hh;
  const int tid = threadIdx.x, w = tid >> 6, l = tid & 63;
  const int l15 = l & 15, lh = l >> 4;
  const int qbase = qb << 6;
  const int qrow0 = qbase + (w << 4);
  short8 aq[4];
#pragma unroll
  for (int kb = 0; kb < 4; kb++)
    aq[kb] = *reinterpret_cast<const short8*>(
        &Q[(size_t)(qrow0 + l15) * C_N + h * D_N + kb * 32 + lh * 8]);
  short8 ones;
#pragma unroll
  for (int j = 0; j < 8; j++) ones[j] = (short)0x3F80;  // bf16 1.0
  f32x4 yacc[8] = {};
  f32x4 lacc = {};
  float m_r = -3.0e38f;            // per-lane: qrow = qrow0 + l15
  const float K2 = 0.12751744f;    // (1/sqrt(128)) * log2(e)
  const float THR = 90.0f;         // defer-max threshold (raw-logit units)
  const int nkt = (1663 + qbase) >> 6;   // >= 25
  const short* psk[4];
  const short* psv[4];
  int ldsoff[4];
#pragma unroll
  for (int it = 0; it < 4; it++) {
    int c = it * 256 + tid;
    int kr = c >> 4, kkc = c & 15;                       // LDS row, chunk
    int pkr = (kr & 0x23) | ((kr & 0x0C) << 1) | ((kr >> 2) & 4);  // pi(row)
    psk[it] = &Kf[(size_t)pkr * KV_N + hk * D_N + ((kkc ^ (kr & 7)) << 3)];
    int vrow = c >> 3, vkc = c & 7;
    psv[it] = &Vt[(size_t)hk * D_N * TOT_N + (size_t)vrow * TOT_N + ((vkc ^ (vrow & 7)) << 3)];
    ldsoff[it] = (it * 256 + w * 64) << 4;
  }
  // prologue: stage K0,V0 then K1,V1 (16 loads/wave in flight)
#pragma unroll
  for (int it = 0; it < 4; it++) gload16(psk[it], (char*)kl + ldsoff[it]);
#pragma unroll
  for (int it = 0; it < 4; it++) gload16(psv[it], (char*)vl + ldsoff[it]);
#pragma unroll
  for (int it = 0; it < 4; it++)
    gload16(psk[it] + 64 * KV_N, (char*)kl + 16384 + ldsoff[it]);
#pragma unroll
  for (int it = 0; it < 4; it++)
    gload16(psv[it] + 64, (char*)vl + 16384 + ldsoff[it]);
  for (int t = 0; t < nkt; t++) {
    // ---- wait K/V(t) landed (K/V(t+1) keep flying), then sync waves
    if (t + 1 < nkt) asm volatile("s_waitcnt vmcnt(8)" ::: "memory");
    else             asm volatile("s_waitcnt vmcnt(0)" ::: "memory");
    __builtin_amdgcn_s_barrier();
    __builtin_amdgcn_sched_barrier(0);
    const char* kbuf = (const char*)kl + ((t & 1) << 14);
    const char* vbuf = (const char*)vl + ((t & 1) << 14);
    // ---- S^T = K Q^T : s[g][r] = S[key][qrow0 + l15]
    f32x4 s[4] = {};
    __builtin_amdgcn_s_setprio(1);
#pragma unroll
    for (int g = 0; g < 4; g++) {
      int row = g * 16 + l15;
#pragma unroll
      for (int kb = 0; kb < 4; kb++) {
        short8 bk = *reinterpret_cast<const short8*>(
            kbuf + row * 256 + ((((kb << 2) + lh) ^ (row & 7)) << 4));
        s[g] = __builtin_amdgcn_mfma_f32_16x16x32_bf16(bk, aq[kb], s[g], 0, 0, 0);
      }
    }
    __builtin_amdgcn_s_setprio(0);
    // ---- mask (boundary tiles only)
    if ((t * 64 + 63) > (1536 + qrow0)) {
      int qi = qrow0 + l15;
#pragma unroll
      for (int g = 0; g < 4; g++)
#pragma unroll
        for (int r = 0; r < 4; r++) {
          int key = t * 64 + ((g >> 1) << 5) + (lh << 3) + ((g & 1) << 2) + r;
          if (key > 1536 + qi) s[g][r] = -3.0e38f;
        }
    }
    // ---- defer-max online softmax (per-lane scalar m)
    float lm = s[0][0];
#pragma unroll
    for (int g = 0; g < 4; g++)
#pragma unroll
      for (int r = 0; r < 4; r++) lm = fmaxf(lm, s[g][r]);
    if (!__all(lm <= m_r + THR)) {
      float rm = fmaxf(lm, __shfl_xor(lm, 16, 64));
      rm = fmaxf(rm, __shfl_xor(rm, 32, 64));
      float mn = fmaxf(m_r, rm);
      float scf = __builtin_amdgcn_exp2f((m_r - mn) * K2);
      m_r = mn;
#pragma unroll
      for (int r = 0; r < 4; r++) {
        float sc_c = __shfl(scf, lh * 4 + r, 64);   // to C-layout row (lh,r)
        lacc[r] *= sc_c;
#pragma unroll
        for (int dg = 0; dg < 8; dg++) yacc[dg][r] *= sc_c;
      }
    }
    // ---- P = exp2(s*K2 - m*K2); pack via v_cvt_pk_bf16_f32 into A-fragments
    const float mk = m_r * K2;
    float pv[16];
#pragma unroll
    for (int g = 0; g < 4; g++)
#pragma unroll
      for (int r = 0; r < 4; r++)
        pv[g * 4 + r] = __builtin_amdgcn_exp2f(s[g][r] * K2 - mk);
    union { i32x4 wv; short8 sv; } u0, u1;
#pragma unroll
    for (int j = 0; j < 4; j++) {
      unsigned w0, w1;
      int g0 = (j >> 1), b0 = g0 * 4 + 2 * (j & 1);
      int g1 = 2 + (j >> 1), b1 = g1 * 4 + 2 * (j & 1);
      asm("v_cvt_pk_bf16_f32 %0, %1, %2" : "=v"(w0) : "v"(pv[b0]), "v"(pv[b0 + 1]));
      asm("v_cvt_pk_bf16_f32 %0, %1, %2" : "=v"(w1) : "v"(pv[b1]), "v"(pv[b1 + 1]));
      u0.wv[j] = (int)w0;
      u1.wv[j] = (int)w1;
    }
    // ---- row sums via mfma(P, ones) -> C-layout (matches epilogue rows)
    lacc = __builtin_amdgcn_mfma_f32_16x16x32_bf16(u0.sv, ones, lacc, 0, 0, 0);
    lacc = __builtin_amdgcn_mfma_f32_16x16x32_bf16(u1.sv, ones, lacc, 0, 0, 0);
    // ---- PV: yacc[dg] += P(16x64) * V(64x128)
    __builtin_amdgcn_s_setprio(1);
#pragma unroll
    for (int dg = 0; dg < 8; dg++) {
      int vrow = dg * 16 + l15;
      short8 bv0 = *reinterpret_cast<const short8*>(
          vbuf + (vrow << 7) + ((lh ^ (vrow & 7)) << 4));
      yacc[dg] = __builtin_amdgcn_mfma_f32_16x16x32_bf16(u0.sv, bv0, yacc[dg], 0, 0, 0);
      short8 bv1 = *reinterpret_cast<const short8*>(
          vbuf + (vrow << 7) + (((4 + lh) ^ (vrow & 7)) << 4));
      yacc[dg] = __builtin_amdgcn_mfma_f32_16x16x32_bf16(u1.sv, bv1, yacc[dg], 0, 0, 0);
    }
    __builtin_amdgcn_s_setprio(0);
    // ---- all waves done reading kl/vl[t&1], then refill with t+2
    asm volatile("s_waitcnt lgkmcnt(0)" ::: "memory");
    __builtin_amdgcn_sched_barrier(0);
    __builtin_amdgcn_s_barrier();
    __builtin_amdgcn_sched_barrier(0);
    if (t + 2 < nkt) {
#pragma unroll
      for (int it = 0; it < 4; it++)
        gload16(psk[it] + (size_t)(t + 2) * 64 * KV_N, (char*)kl + ((t & 1) << 14) + ldsoff[it]);
#pragma unroll
      for (int it = 0; it < 4; it++)
        gload16(psv[it] + (size_t)(t + 2) * 64, (char*)vl + ((t & 1) << 14) + ldsoff[it]);
    }
  }
  // ---- epilogue
#pragma unroll
  for (int dg = 0; dg < 8; dg++)
#pragma unroll
    for (int r = 0; r < 4; r++) {
      int row = qrow0 + lh * 4 + r;
      int col = h * D_N + dg * 16 + l15;
      Y[(size_t)row * C_N + col] = f2bf(yacc[dg][r] / lacc[r]);
    }
}

// ---------------- host launcher ----------------
extern "C" void kernel_launch(void* const* d_in, const int* in_sizes, int n_in,
                              void* d_out, int out_size, void* d_ws, size_t ws_size,
                              hipStream_t stream) {
  const float* x      = (const float*)d_in[0];
  const float* stm    = (const float*)d_in[1];
  // d_in[2] = long_q: unused (its query rows are discarded by y[:, -T:])
  const float* long_k = (const float*)d_in[3];
  const float* long_v = (const float*)d_in[4];
  const float* Wq     = (const float*)d_in[5];
  const float* Wk     = (const float*)d_in[6];
  const float* Wv     = (const float*)d_in[7];
  const float* Wo     = (const float*)d_in[8];
  float* out = (float*)d_out;

  // ---- workspace carve (bf16 stored as short) ----
  short* seq  = (short*)d_ws;                       // [2560][2048]
  short* WqT  = seq  + (size_t)ST_N * C_N;          // [2048][2048]  } contiguous:
  short* WkT  = WqT  + (size_t)C_N * C_N;           // [512][2048]   } Bt for merged
  short* WvT  = WkT  + (size_t)KV_N * C_N;          // [512][2048]   } QKV gemm
  short* WoT  = WvT  + (size_t)KV_N * C_N;          // [2048][2048]
  short* qbuf = WoT  + (size_t)C_N * C_N;           // [2048][2048]
  short* Kf   = qbuf + (size_t)T_N * C_N;           // [3584][512]
  short* Vf   = Kf   + (size_t)TOT_N * KV_N;        // [3584][512]
  short* Vt   = Vf   + (size_t)TOT_N * KV_N;        // [4][128][3584]
  short* ybuf = Vt   + (size_t)TOT_N * KV_N;        // [2048][2048]
  float* ctab = (float*)(ybuf + (size_t)T_N * C_N); // [2560][64]
  float* stab = ctab + (size_t)ST_N * 64;

  // ---- fused converts + RoPE tables (1 launch) ----
  k_setup<<<TAB_E / 256, 256, 0, stream>>>(x, stm, long_k, long_v, seq, Kf, Vf, ctab, stab);

  // ---- fused weight transposes (1 launch) ----
  k_tconv_all<<<dim3(64, 64, 4), dim3(32, 8), 0, stream>>>(
      Wq, Wk, Wv, Wo, WqT, WkT, WvT, WoT);

  // ---- merged QKV projection + fused RoPE epilogue (480 blocks) ----
  k_gemm_qkv<<<dim3(3072 / 128, ST_N / 128), 256, 0, stream>>>(
      seq, WqT, qbuf, Kf, Vf, ctab, stab);

  // ---- V transpose per kv-head ----
  k_tv<<<dim3(TOT_N / 32, D_N / 32, HK_N), dim3(32, 8), 0, stream>>>(Vf, Vt);

  // ---- attention ----
  k_attn<<<512, 256, 0, stream>>>(qbuf, Kf, Vt, ybuf);

  // ---- output projection (f32 out) ----
  k_gemm<true><<<dim3(C_N / 128, T_N / 128), 256, 0, stream>>>(ybuf, WoT, out, T_N, C_N, C_N);
}